// Round 6
// baseline (375.321 us; speedup 1.0000x reference)
//
#include <hip/hip_runtime.h>
#include <hip/hip_cooperative_groups.h>
#include <hip/hip_bf16.h>
#include <math.h>

namespace cg = cooperative_groups;

typedef __bf16 bf16x8 __attribute__((ext_vector_type(8)));
typedef float f32x4 __attribute__((ext_vector_type(4)));

__device__ __forceinline__ unsigned short f2bf(float x) {
    union { float f; unsigned int u; } v; v.f = x;
    unsigned int r = v.u + 0x7fffu + ((v.u >> 16) & 1u);  // round-to-nearest-even
    return (unsigned short)(r >> 16);
}
__device__ __forceinline__ float gelu_exact(float v) {
    return 0.5f * v * (1.0f + erff(v * 0.70710678118654752f));
}

// pool exactly N rows starting at s (compile-time N; loads issued back-to-back,
// summed ascending -> identical fp order to the R2/R4-verified path)
template<int N>
__device__ __forceinline__ void pool_sum(const float4* __restrict__ base, int s, int tid, float4& out) {
    float4 v[N];
#pragma unroll
    for (int t = 0; t < N; ++t) v[t] = base[(s + t) * 256 + tid];
    float x = 0.f, y = 0.f, z = 0.f, w = 0.f;
#pragma unroll
    for (int t = 0; t < N; ++t) { x += v[t].x; y += v[t].y; z += v[t].z; w += v[t].w; }
    const float inv = 1.0f / (float)N;
    out.x = x * inv; out.y = y * inv; out.z = z * inv; out.w = w * inv;
}
__device__ __forceinline__ void pool_dispatch(const float4* __restrict__ base, int s, int len, int tid, float4& out) {
    switch (len) {   // len is block-uniform -> uniform jump, no divergence
        case 1: pool_sum<1>(base, s, tid, out); break;
        case 2: pool_sum<2>(base, s, tid, out); break;
        case 3: pool_sum<3>(base, s, tid, out); break;
        case 4: pool_sum<4>(base, s, tid, out); break;
        case 5: pool_sum<5>(base, s, tid, out); break;
        case 6: pool_sum<6>(base, s, tid, out); break;
        case 7: pool_sum<7>(base, s, tid, out); break;
        default: pool_sum<8>(base, s, tid, out); break;
    }
}

// ---------------------------------------------------------------------------
// fused_all: whole pipeline in ONE cooperative kernel. grid 512 x 256 thr,
// 2 blocks/CU (proven gemm1 occupancy; LDS union 72 KB -> 144/160 KB per CU).
// Phase A: pooling (8 pairs/block, block pools a subset of its own phase-B
//          A-rows) + W1/W2 bf16 convert.  [R4-verified logic]
// Phase B: gemm1 BM=32 BN=64 BK=192, XOR-swizzled global_load_lds double
//          buffer, XCD sibling co-location.  [R4-verified, byte-identical]
// Phase C: blocks 0..127: GEMM2 with A-frags direct from L2-hot x1 (16B
//          global loads, no Xs staging), Ws staged swizzled; head reduced
//          in registers via __shfl_xor; no X2 LDS round-trip.
// grid.sync() between phases (device-scope release/acquire handles the
// cross-XCD L2 visibility of hp/w1b/x1/w2b).
// ---------------------------------------------------------------------------
__global__ __launch_bounds__(256, 2) void fused_all(
        const float* __restrict__ hs, const int* __restrict__ spans,
        const float* __restrict__ W1, const float* __restrict__ b1,
        const float* __restrict__ W2, const float* __restrict__ b2,
        const float* __restrict__ W3, const float* __restrict__ b3,
        const float* __restrict__ mask, float* __restrict__ out,
        unsigned short* __restrict__ hp, unsigned short* __restrict__ w1b,
        unsigned short* __restrict__ x1, unsigned short* __restrict__ w2b) {
    __shared__ __align__(16) unsigned char smem[73728];      // 72 KB union
    unsigned short* As = (unsigned short*)smem;              // B: 24 KB
    unsigned short* Bs = (unsigned short*)(smem + 24576);    // B: 48 KB
    unsigned short* Ws = (unsigned short*)smem;              // C: 64 KB
    float*      scratch = (float*)(smem + 65536);            // C: 512 B

    const int tid = threadIdx.x;
    const int id = blockIdx.x;            // 0..511
    const int lane = tid & 63;
    const int wid = tid >> 6;
    const int quad = lane >> 4;
    const int l16 = lane & 15;

    // XCD co-location: id%8 = XCD; XCD k owns M-panels [k*16, (k+1)*16) x 4 N
    const int xcd = id & 7;
    const int sub = id >> 3;              // 0..63
    const int mp = xcd * 16 + (sub >> 2); // m-panel 0..127
    const int jj = sub & 3;               // N-sibling 0..3
    const int m0 = mp * 32;
    const int n0 = jj * 64;

    // ================= Phase A: pooling + weight convert =================
    {
        const bool is64 = (spans[1] == 0);
        for (int pp = 0; pp < 8; ++pp) {
            const int pair = m0 + jj * 8 + pp;    // block pools 8 of its own 32 A-rows
            const int b = pair >> 7;
            int s_a, e_a, s_o, e_o;
            if (is64) {
                s_a = spans[(pair * 4 + 0) * 2]; e_a = spans[(pair * 4 + 1) * 2];
                s_o = spans[(pair * 4 + 2) * 2]; e_o = spans[(pair * 4 + 3) * 2];
            } else {
                s_a = spans[pair * 4 + 0]; e_a = spans[pair * 4 + 1];
                s_o = spans[pair * 4 + 2]; e_o = spans[pair * 4 + 3];
            }
            if (!(s_a >= 2 && e_a >= s_a)) { s_a = 1; e_a = 1; }
            if (!(s_o >= 2 && e_o >= s_o)) { s_o = 1; e_o = 1; }
            const float4* base = (const float4*)hs + (size_t)b * 512 * 256;
            float4 A, O;
            pool_dispatch(base, s_a, e_a - s_a + 1, tid, A);
            pool_dispatch(base, s_o, e_o - s_o + 1, tid, O);

            unsigned short* row = hp + (size_t)pair * 3072;
            const int d = tid * 4;
            ushort4 pa, po, pq;
            pa.x = f2bf(A.x); pa.y = f2bf(A.y); pa.z = f2bf(A.z); pa.w = f2bf(A.w);
            po.x = f2bf(O.x); po.y = f2bf(O.y); po.z = f2bf(O.z); po.w = f2bf(O.w);
            pq.x = f2bf(A.x * O.x); pq.y = f2bf(A.y * O.y);
            pq.z = f2bf(A.z * O.z); pq.w = f2bf(A.w * O.w);
            *(ushort4*)(row + d) = pa;
            *(ushort4*)(row + 1024 + d) = po;
            *(ushort4*)(row + 2048 + d) = pq;
        }
        // W1 convert: 196608 float4s over 131072 threads (1-2 each)
        const int g = id * 256 + tid;
        {
            float4 f = ((const float4*)W1)[g];
            ushort4 u;
            u.x = f2bf(f.x); u.y = f2bf(f.y); u.z = f2bf(f.z); u.w = f2bf(f.w);
            ((ushort4*)w1b)[g] = u;
            const int g2 = g + 131072;
            if (g2 < 196608) {
                float4 f2 = ((const float4*)W1)[g2];
                ushort4 u2;
                u2.x = f2bf(f2.x); u2.y = f2bf(f2.y); u2.z = f2bf(f2.z); u2.w = f2bf(f2.w);
                ((ushort4*)w1b)[g2] = u2;
            }
        }
        if (g < 8192) {                        // W2 convert
            float4 f = ((const float4*)W2)[g];
            ushort4 u;
            u.x = f2bf(f.x); u.y = f2bf(f.y); u.z = f2bf(f.z); u.w = f2bf(f.w);
            ((ushort4*)w2b)[g] = u;
        }
    }
    __threadfence();
    cg::this_grid().sync();

    // ================= Phase B: gemm1 (R4-verified body) =================
    {
        const unsigned short* Ap = hp;
        const unsigned short* Bw = w1b;

        const unsigned short* Aptr[3];
#pragma unroll
        for (int p = 0; p < 3; ++p) {
            const int s = p * 256 + tid;
            const int row = s / 24;
            const int c = s - row * 24;
            const int lch = (c & 24) | ((c & 7) ^ (row & 7));
            Aptr[p] = Ap + (size_t)(m0 + row) * 3072 + lch * 8;
        }
        const unsigned short* Bptr[6];
#pragma unroll
        for (int p = 0; p < 6; ++p) {
            const int s = p * 256 + tid;
            const int row = s / 24;
            const int c = s - row * 24;
            const int lch = (c & 24) | ((c & 7) ^ (row & 7));
            Bptr[p] = Bw + (size_t)(n0 + row) * 3072 + lch * 8;
        }

        int aoff[2][6], boff[6];
#pragma unroll
        for (int h = 0; h < 6; ++h) {
            const int c = h * 4 + quad;
#pragma unroll
            for (int mh = 0; mh < 2; ++mh) {
                const int row = mh * 16 + l16;
                const int pc = (c & 24) | ((c & 7) ^ (row & 7));
                aoff[mh][h] = row * 192 + pc * 8;
            }
            const int brow = wid * 16 + l16;
            const int pcb = (c & 24) | ((c & 7) ^ (brow & 7));
            boff[h] = brow * 192 + pcb * 8;
        }

        f32x4 acc[2] = {};

#pragma unroll
        for (int p = 0; p < 3; ++p)
            __builtin_amdgcn_global_load_lds(
                (const __attribute__((address_space(1))) void*)Aptr[p],
                (__attribute__((address_space(3))) void*)(&As[(p * 256 + tid) * 8]), 16, 0, 0);
#pragma unroll
        for (int p = 0; p < 6; ++p)
            __builtin_amdgcn_global_load_lds(
                (const __attribute__((address_space(1))) void*)Bptr[p],
                (__attribute__((address_space(3))) void*)(&Bs[(p * 256 + tid) * 8]), 16, 0, 0);

        for (int it = 0; it < 16; ++it) {
            const int cur = it & 1;
            __syncthreads();                  // drains pending stage (vmcnt 0)
            if (it + 1 < 16) {
                const int nxt = cur ^ 1;
                const int kadv = (it + 1) * 192;
#pragma unroll
                for (int p = 0; p < 3; ++p)
                    __builtin_amdgcn_global_load_lds(
                        (const __attribute__((address_space(1))) void*)(Aptr[p] + kadv),
                        (__attribute__((address_space(3))) void*)(&As[nxt * 6144 + (p * 256 + tid) * 8]), 16, 0, 0);
#pragma unroll
                for (int p = 0; p < 6; ++p)
                    __builtin_amdgcn_global_load_lds(
                        (const __attribute__((address_space(1))) void*)(Bptr[p] + kadv),
                        (__attribute__((address_space(3))) void*)(&Bs[nxt * 12288 + (p * 256 + tid) * 8]), 16, 0, 0);
            }
#pragma unroll
            for (int h = 0; h < 6; ++h) {
                bf16x8 bfr = *(const bf16x8*)&Bs[cur * 12288 + boff[h]];
#pragma unroll
                for (int mh = 0; mh < 2; ++mh) {
                    bf16x8 afr = *(const bf16x8*)&As[cur * 6144 + aoff[mh][h]];
                    acc[mh] = __builtin_amdgcn_mfma_f32_16x16x32_bf16(afr, bfr, acc[mh], 0, 0, 0);
                }
            }
        }

        const int n = n0 + wid * 16 + l16;
        const float bn = b1[n];
#pragma unroll
        for (int mh = 0; mh < 2; ++mh) {
#pragma unroll
            for (int rr = 0; rr < 4; ++rr) {
                const int m = m0 + mh * 16 + quad * 4 + rr;
                x1[(size_t)m * 256 + n] = f2bf(gelu_exact(acc[mh][rr] + bn));
            }
        }
    }
    __threadfence();
    cg::this_grid().sync();

    // ================= Phase C: GEMM2 + head (blocks 0..127) =============
    if (id >= 128) return;
    {
        const int m0c = id * 32;
        const int wM = (wid >> 1) * 16;       // waves 2x2: 16 pairs x 64 cols
        const int wN = (wid & 1) * 64;
        const int half = wid & 1;

        // stage Ws: 4096 slots of 16B, XOR chunk swizzle (verified pattern)
#pragma unroll
        for (int p = 0; p < 16; ++p) {
            const int s = p * 256 + tid;
            const int row = s >> 5;
            const int c = s & 31;
            const int lch = (c & 24) | ((c & 7) ^ (row & 7));
            __builtin_amdgcn_global_load_lds(
                (const __attribute__((address_space(1))) void*)(w2b + (size_t)row * 256 + lch * 8),
                (__attribute__((address_space(3))) void*)(&Ws[s * 8]), 16, 0, 0);
        }
        __syncthreads();

        // GEMM2: A-frags direct from global x1 (L2-hot), B from Ws
        f32x4 acc2[4] = {};
        const unsigned short* arow = x1 + (size_t)(m0c + wM + l16) * 256;
#pragma unroll
        for (int h = 0; h < 8; ++h) {
            bf16x8 afr = *(const bf16x8*)(arow + h * 32 + quad * 8);
#pragma unroll
            for (int ni = 0; ni < 4; ++ni) {
                const int rowb = wN + ni * 16 + l16;
                const int c = h * 4 + quad;
                const int pcb = (c & 24) | ((c & 7) ^ (rowb & 7));
                bf16x8 bfr = *(const bf16x8*)&Ws[rowb * 256 + pcb * 8];
                acc2[ni] = __builtin_amdgcn_mfma_f32_16x16x32_bf16(afr, bfr, acc2[ni], 0, 0, 0);
            }
        }

        // head from registers: x2 = gelu(acc2 + b2); dot with W3 rows; reduce
        float b2v[4], w30[4], w31[4];
#pragma unroll
        for (int ni = 0; ni < 4; ++ni) {
            const int col = wN + ni * 16 + l16;
            b2v[ni] = b2[col]; w30[ni] = W3[col]; w31[ni] = W3[128 + col];
        }
#pragma unroll
        for (int rr = 0; rr < 4; ++rr) {
            float t0 = 0.f, t1 = 0.f;
#pragma unroll
            for (int ni = 0; ni < 4; ++ni) {
                const float xv = gelu_exact(acc2[ni][rr] + b2v[ni]);
                t0 += xv * w30[ni]; t1 += xv * w31[ni];
            }
            t0 += __shfl_xor(t0, 1); t0 += __shfl_xor(t0, 2);
            t0 += __shfl_xor(t0, 4); t0 += __shfl_xor(t0, 8);
            t1 += __shfl_xor(t1, 1); t1 += __shfl_xor(t1, 2);
            t1 += __shfl_xor(t1, 4); t1 += __shfl_xor(t1, 8);
            if (l16 == 0) {
                const int pb = wM + quad * 4 + rr;   // pair-in-block 0..31
                scratch[(half * 32 + pb) * 2 + 0] = t0;
                scratch[(half * 32 + pb) * 2 + 1] = t1;
            }
        }
        __syncthreads();
        if (tid < 64) {
            const int pb = tid >> 1, o = tid & 1;
            const float v = scratch[pb * 2 + o] + scratch[(32 + pb) * 2 + o];
            const int pair = m0c + pb;
            const float mk = (mask[pair] >= 0.5f) ? 1.0f : 0.0f;
            out[pair * 2 + o] = ((1.0f / (1.0f + expf(-(v + b3[o])))) * 8.0f + 1.0f) * mk;
        }
    }
}

// ---------------------------------------------------------------------------
extern "C" void kernel_launch(void* const* d_in, const int* in_sizes, int n_in,
                              void* d_out, int out_size, void* d_ws, size_t ws_size,
                              hipStream_t stream) {
    const float* hs   = (const float*)d_in[0];
    const int*   spans= (const int*)d_in[1];
    const float* mask = (const float*)d_in[2];
    const float* W1   = (const float*)d_in[3];
    const float* b1   = (const float*)d_in[4];
    const float* W2   = (const float*)d_in[5];
    const float* b2   = (const float*)d_in[6];
    const float* W3   = (const float*)d_in[7];
    const float* b3   = (const float*)d_in[8];
    float* out = (float*)d_out;

    // ws: hp bf16 4096x3072 [0, 25165824); w1b bf16 256x3072 [25165824, +1.5MB);
    // x1 bf16 4096x256 [26738688, +2MB); w2b bf16 128x256 [28835840, +64KB).
    unsigned short* hp  = (unsigned short*)d_ws;
    unsigned short* w1b = (unsigned short*)((char*)d_ws + 25165824);
    unsigned short* x1  = (unsigned short*)((char*)d_ws + 26738688);
    unsigned short* w2b = (unsigned short*)((char*)d_ws + 28835840);

    void* args[] = { (void*)&hs, (void*)&spans, (void*)&W1, (void*)&b1,
                     (void*)&W2, (void*)&b2, (void*)&W3, (void*)&b3,
                     (void*)&mask, (void*)&out,
                     (void*)&hp, (void*)&w1b, (void*)&x1, (void*)&w2b };
    hipLaunchCooperativeKernel((const void*)fused_all, dim3(512), dim3(256),
                               args, 0, stream);
}

// Round 9
// 167.658 us; speedup vs baseline: 2.2386x; 2.2386x over previous
//
#include <hip/hip_runtime.h>
#include <hip/hip_bf16.h>
#include <math.h>

typedef __bf16 bf16x8 __attribute__((ext_vector_type(8)));
typedef float f32x4 __attribute__((ext_vector_type(4)));

__device__ __forceinline__ unsigned short f2bf(float x) {
    union { float f; unsigned int u; } v; v.f = x;
    unsigned int r = v.u + 0x7fffu + ((v.u >> 16) & 1u);  // round-to-nearest-even
    return (unsigned short)(r >> 16);
}
__device__ __forceinline__ float gelu_exact(float v) {
    return 0.5f * v * (1.0f + erff(v * 0.70710678118654752f));
}

// pool exactly N rows starting at s (N is a compile-time case; loads issued
// back-to-back, summed ascending -> identical fp order to the R2-verified path)
template<int N>
__device__ __forceinline__ void pool_sum(const float4* __restrict__ base, int s, int tid, float4& out) {
    float4 v[N];
#pragma unroll
    for (int t = 0; t < N; ++t) v[t] = base[(s + t) * 256 + tid];
    float x = 0.f, y = 0.f, z = 0.f, w = 0.f;
#pragma unroll
    for (int t = 0; t < N; ++t) { x += v[t].x; y += v[t].y; z += v[t].z; w += v[t].w; }
    const float inv = 1.0f / (float)N;
    out.x = x * inv; out.y = y * inv; out.z = z * inv; out.w = w * inv;
}

__device__ __forceinline__ void pool_dispatch(const float4* __restrict__ base, int s, int len, int tid, float4& out) {
    // len is wave-uniform (whole block shares one pair) -> uniform jump, no divergence
    switch (len) {
        case 1: pool_sum<1>(base, s, tid, out); break;
        case 2: pool_sum<2>(base, s, tid, out); break;
        case 3: pool_sum<3>(base, s, tid, out); break;
        case 4: pool_sum<4>(base, s, tid, out); break;
        case 5: pool_sum<5>(base, s, tid, out); break;
        case 6: pool_sum<6>(base, s, tid, out); break;
        case 7: pool_sum<7>(base, s, tid, out); break;
        default: pool_sum<8>(base, s, tid, out); break;
    }
}

// ---------------------------------------------------------------------------
// prep: blocks [0,4096)    -> span pooling into hp (4096 x 3072 bf16)
//       blocks [4096,4864) -> W1 fp32 -> bf16 (256x3072)
//       blocks [4864,4896) -> W2 fp32 -> bf16 (128x256)
// R4-verified exact-length pooling.
// ---------------------------------------------------------------------------
__global__ __launch_bounds__(256) void prep_kernel(const float* __restrict__ hs,
                                                   const int* __restrict__ spans,
                                                   const float* __restrict__ W1,
                                                   const float* __restrict__ W2,
                                                   unsigned short* __restrict__ hp,
                                                   unsigned short* __restrict__ w1b,
                                                   unsigned short* __restrict__ w2b) {
    const int blk = blockIdx.x;
    const int tid = threadIdx.x;

    if (blk >= 4096) {
        if (blk < 4864) {                     // W1 convert: 196608 float4s
            const int i = (blk - 4096) * 256 + tid;
            float4 f = ((const float4*)W1)[i];
            ushort4 u;
            u.x = f2bf(f.x); u.y = f2bf(f.y); u.z = f2bf(f.z); u.w = f2bf(f.w);
            ((ushort4*)w1b)[i] = u;
        } else {                              // W2 convert: 8192 float4s
            const int i = (blk - 4864) * 256 + tid;
            float4 f = ((const float4*)W2)[i];
            ushort4 u;
            u.x = f2bf(f.x); u.y = f2bf(f.y); u.z = f2bf(f.z); u.w = f2bf(f.w);
            ((ushort4*)w2b)[i] = u;
        }
        return;
    }

    const int pair = blk;                     // b*Q + q, Q=128
    const int b = pair >> 7;

    // dtype probe: int64 spans -> word 1 is high half of asp_s[0] (== 0);
    // int32 spans -> it's asp_e[0] which is always >= 2.
    const bool is64 = (spans[1] == 0);
    int s_a, e_a, s_o, e_o;
    if (is64) {
        s_a = spans[(pair * 4 + 0) * 2]; e_a = spans[(pair * 4 + 1) * 2];
        s_o = spans[(pair * 4 + 2) * 2]; e_o = spans[(pair * 4 + 3) * 2];
    } else {
        s_a = spans[pair * 4 + 0]; e_a = spans[pair * 4 + 1];
        s_o = spans[pair * 4 + 2]; e_o = spans[pair * 4 + 3];
    }

    // invalid span -> pool over row 1 only (== sep token)
    if (!(s_a >= 2 && e_a >= s_a)) { s_a = 1; e_a = 1; }
    if (!(s_o >= 2 && e_o >= s_o)) { s_o = 1; e_o = 1; }
    const int lenA = e_a - s_a + 1;           // 1..8
    const int lenO = e_o - s_o + 1;           // 1..8

    const float4* base = (const float4*)hs + (size_t)b * 512 * 256;  // L=512, H/4=256

    float4 A, O;
    pool_dispatch(base, s_a, lenA, tid, A);
    pool_dispatch(base, s_o, lenO, tid, O);

    unsigned short* row = hp + (size_t)pair * 3072;
    const int d = tid * 4;
    ushort4 pa, po, pp;
    pa.x = f2bf(A.x); pa.y = f2bf(A.y); pa.z = f2bf(A.z); pa.w = f2bf(A.w);
    po.x = f2bf(O.x); po.y = f2bf(O.y); po.z = f2bf(O.z); po.w = f2bf(O.w);
    pp.x = f2bf(A.x * O.x); pp.y = f2bf(A.y * O.y);
    pp.z = f2bf(A.z * O.z); pp.w = f2bf(A.w * O.w);
    *(ushort4*)(row + d) = pa;
    *(ushort4*)(row + 1024 + d) = po;
    *(ushort4*)(row + 2048 + d) = pp;
}

// ---------------------------------------------------------------------------
// gemm1_gelu v4 (R4-verified): BM=32, BN=64, BK=192, grid 512 1-D, 2 blk/CU,
// XCD sibling co-location. NOTE (R6 measurement round): this kernel is
// launched TWICE back-to-back — it is deterministic and idempotent, so the
// dur_us delta vs the single-launch baseline measures t_gemm1 exactly.
// ---------------------------------------------------------------------------
__global__ __launch_bounds__(256, 2) void gemm1_gelu(const unsigned short* __restrict__ A,
                                                     const unsigned short* __restrict__ Bw,
                                                     const float* __restrict__ b1,
                                                     unsigned short* __restrict__ x1) {
    __shared__ __align__(16) unsigned short As[2 * 32 * 192];   // 24 KB
    __shared__ __align__(16) unsigned short Bs[2 * 64 * 192];   // 48 KB

    const int tid = threadIdx.x;
    const int lane = tid & 63;
    const int wid = tid >> 6;
    const int quad = lane >> 4;
    const int l16 = lane & 15;

    // XCD co-location: id%8 = XCD; XCD k owns M-panels [k*16, k*16+16) x all 4 N
    const int id = blockIdx.x;                // 0..511
    const int xcd = id & 7;
    const int sub = id >> 3;                  // 0..63
    const int m0 = (xcd * 16 + (sub >> 2)) * 32;
    const int n0 = (sub & 3) * 64;

    // staging sources: slot s (16B) -> row = s/24, chunk c = s%24, XOR-swizzled
    const unsigned short* Aptr[3];
#pragma unroll
    for (int p = 0; p < 3; ++p) {
        const int s = p * 256 + tid;          // 0..767
        const int row = s / 24;
        const int c = s - row * 24;
        const int lch = (c & 24) | ((c & 7) ^ (row & 7));
        Aptr[p] = A + (size_t)(m0 + row) * 3072 + lch * 8;
    }
    const unsigned short* Bptr[6];
#pragma unroll
    for (int p = 0; p < 6; ++p) {
        const int s = p * 256 + tid;          // 0..1535
        const int row = s / 24;
        const int c = s - row * 24;
        const int lch = (c & 24) | ((c & 7) ^ (row & 7));
        Bptr[p] = Bw + (size_t)(n0 + row) * 3072 + lch * 8;
    }

    // fragment LDS offsets (halfwords): K-frag h (6 per iter), chunk c = h*4+quad
    int aoff[2][6], boff[6];
#pragma unroll
    for (int h = 0; h < 6; ++h) {
        const int c = h * 4 + quad;
#pragma unroll
        for (int mh = 0; mh < 2; ++mh) {
            const int row = mh * 16 + l16;
            const int pc = (c & 24) | ((c & 7) ^ (row & 7));
            aoff[mh][h] = row * 192 + pc * 8;
        }
        const int brow = wid * 16 + l16;
        const int pcb = (c & 24) | ((c & 7) ^ (brow & 7));
        boff[h] = brow * 192 + pcb * 8;
    }

    f32x4 acc[2] = {};

    // prologue: tile 0 -> buffer 0
#pragma unroll
    for (int p = 0; p < 3; ++p)
        __builtin_amdgcn_global_load_lds(
            (const __attribute__((address_space(1))) void*)Aptr[p],
            (__attribute__((address_space(3))) void*)(&As[(p * 256 + tid) * 8]), 16, 0, 0);
#pragma unroll
    for (int p = 0; p < 6; ++p)
        __builtin_amdgcn_global_load_lds(
            (const __attribute__((address_space(1))) void*)Bptr[p],
            (__attribute__((address_space(3))) void*)(&Bs[(p * 256 + tid) * 8]), 16, 0, 0);

    for (int it = 0; it < 16; ++it) {
        const int cur = it & 1;
        __syncthreads();                      // drains pending stage (vmcnt 0)
        if (it + 1 < 16) {
            const int nxt = cur ^ 1;
            const int kadv = (it + 1) * 192;  // halfwords along K
#pragma unroll
            for (int p = 0; p < 3; ++p)
                __builtin_amdgcn_global_load_lds(
                    (const __attribute__((address_space(1))) void*)(Aptr[p] + kadv),
                    (__attribute__((address_space(3))) void*)(&As[nxt * 6144 + (p * 256 + tid) * 8]), 16, 0, 0);
#pragma unroll
            for (int p = 0; p < 6; ++p)
                __builtin_amdgcn_global_load_lds(
                    (const __attribute__((address_space(1))) void*)(Bptr[p] + kadv),
                    (__attribute__((address_space(3))) void*)(&Bs[nxt * 12288 + (p * 256 + tid) * 8]), 16, 0, 0);
        }
#pragma unroll
        for (int h = 0; h < 6; ++h) {
            bf16x8 b = *(const bf16x8*)&Bs[cur * 12288 + boff[h]];
#pragma unroll
            for (int mh = 0; mh < 2; ++mh) {
                bf16x8 a = *(const bf16x8*)&As[cur * 6144 + aoff[mh][h]];
                acc[mh] = __builtin_amdgcn_mfma_f32_16x16x32_bf16(a, b, acc[mh], 0, 0, 0);
            }
        }
    }

    // epilogue: bias + gelu -> bf16; C/D map: col=l16, row=quad*4+reg
    const int n = n0 + wid * 16 + l16;
    const float bn = b1[n];
#pragma unroll
    for (int mh = 0; mh < 2; ++mh) {
#pragma unroll
        for (int rr = 0; rr < 4; ++rr) {
            const int m = m0 + mh * 16 + quad * 4 + rr;
            x1[(size_t)m * 256 + n] = f2bf(gelu_exact(acc[mh][rr] + bn));
        }
    }
}

// ---------------------------------------------------------------------------
// mlp2_head v2 (single-stage): 32 pairs/block, grid 128. (unchanged, verified)
// ---------------------------------------------------------------------------
__global__ __launch_bounds__(256) void mlp2_head(const unsigned short* __restrict__ x1,
                                                 const unsigned short* __restrict__ w2b,
                                                 const float* __restrict__ b2,
                                                 const float* __restrict__ W3,
                                                 const float* __restrict__ b3,
                                                 const float* __restrict__ mask,
                                                 float* __restrict__ out) {
    __shared__ __align__(16) unsigned char smem[98304];
    unsigned short* Xs = (unsigned short*)smem;            // 32 x 256 hw (swizzled)
    unsigned short* Ws = (unsigned short*)(smem + 16384);  // 128 x 256 hw (swizzled)
    float*          X2 = (float*)(smem + 81920);           // 32 x 128 fp32

    const int tid = threadIdx.x;
    const int lane = tid & 63;
    const int wid = tid >> 6;
    const int quad = lane >> 4;
    const int l16 = lane & 15;
    const int wM = (wid >> 1) * 16;   // waves 2x2: wave tile 16 pairs x 64 cols
    const int wN = (wid & 1) * 64;
    const int m0 = blockIdx.x * 32;

    // stage Xs: 1024 slots; slot s -> row=s>>5, c=s&31, swizzled source chunk
#pragma unroll
    for (int p = 0; p < 4; ++p) {
        const int s = p * 256 + tid;
        const int row = s >> 5;
        const int c = s & 31;
        const int lch = (c & 24) | ((c & 7) ^ (row & 7));
        __builtin_amdgcn_global_load_lds(
            (const __attribute__((address_space(1))) void*)(x1 + (size_t)(m0 + row) * 256 + lch * 8),
            (__attribute__((address_space(3))) void*)(&Xs[s * 8]), 16, 0, 0);
    }
    // stage Ws: 4096 slots
#pragma unroll
    for (int p = 0; p < 16; ++p) {
        const int s = p * 256 + tid;
        const int row = s >> 5;
        const int c = s & 31;
        const int lch = (c & 24) | ((c & 7) ^ (row & 7));
        __builtin_amdgcn_global_load_lds(
            (const __attribute__((address_space(1))) void*)(w2b + (size_t)row * 256 + lch * 8),
            (__attribute__((address_space(3))) void*)(&Ws[s * 8]), 16, 0, 0);
    }
    __syncthreads();

    // GEMM2: 8 K-frags, 4 MFMA each per wave
    f32x4 acc[4] = {};
#pragma unroll
    for (int h = 0; h < 8; ++h) {
        const int c = h * 4 + quad;
        const int rowa = wM + l16;
        const int pca = (c & 24) | ((c & 7) ^ (rowa & 7));
        bf16x8 a = *(const bf16x8*)&Xs[rowa * 256 + pca * 8];
#pragma unroll
        for (int ni = 0; ni < 4; ++ni) {
            const int rowb = wN + ni * 16 + l16;
            const int pcb = (c & 24) | ((c & 7) ^ (rowb & 7));
            bf16x8 b = *(const bf16x8*)&Ws[rowb * 256 + pcb * 8];
            acc[ni] = __builtin_amdgcn_mfma_f32_16x16x32_bf16(a, b, acc[ni], 0, 0, 0);
        }
    }

    // x2 = gelu(acc + b2) -> X2 (fp32 LDS)
#pragma unroll
    for (int ni = 0; ni < 4; ++ni) {
        const int n = wN + ni * 16 + l16;
        const float bn = b2[n];
#pragma unroll
        for (int rr = 0; rr < 4; ++rr) {
            const int m = wM + quad * 4 + rr;
            X2[m * 128 + n] = gelu_exact(acc[ni][rr] + bn);
        }
    }
    __syncthreads();

    // head: 8 threads per pair, 16 cols each
    const int p = tid >> 3;           // pair-in-block 0..31
    const int cc = (tid & 7) * 16;
    float a0 = 0.f, a1 = 0.f;
#pragma unroll
    for (int j = 0; j < 16; ++j) {
        const float xv = X2[p * 128 + cc + j];
        a0 += xv * W3[cc + j];
        a1 += xv * W3[128 + cc + j];
    }
    a0 += __shfl_xor(a0, 1); a0 += __shfl_xor(a0, 2); a0 += __shfl_xor(a0, 4);
    a1 += __shfl_xor(a1, 1); a1 += __shfl_xor(a1, 2); a1 += __shfl_xor(a1, 4);
    if ((tid & 7) == 0) {
        const int pair = m0 + p;
        const float mk = (mask[pair] >= 0.5f) ? 1.0f : 0.0f;
        out[pair * 2 + 0] = ((1.0f / (1.0f + expf(-(a0 + b3[0])))) * 8.0f + 1.0f) * mk;
        out[pair * 2 + 1] = ((1.0f / (1.0f + expf(-(a1 + b3[1])))) * 8.0f + 1.0f) * mk;
    }
}

// ---------------------------------------------------------------------------
extern "C" void kernel_launch(void* const* d_in, const int* in_sizes, int n_in,
                              void* d_out, int out_size, void* d_ws, size_t ws_size,
                              hipStream_t stream) {
    const float* hs   = (const float*)d_in[0];
    const int*   spans= (const int*)d_in[1];
    const float* mask = (const float*)d_in[2];
    const float* W1   = (const float*)d_in[3];
    const float* b1   = (const float*)d_in[4];
    const float* W2   = (const float*)d_in[5];
    const float* b2   = (const float*)d_in[6];
    const float* W3   = (const float*)d_in[7];
    const float* b3   = (const float*)d_in[8];
    float* out = (float*)d_out;

    // ws: hp bf16 4096x3072 [0, 25165824); w1b bf16 256x3072 [25165824, +1.5MB);
    // x1 bf16 4096x256 [26738688, +2MB); w2b bf16 128x256 [28835840, +64KB).
    unsigned short* hp  = (unsigned short*)d_ws;
    unsigned short* w1b = (unsigned short*)((char*)d_ws + 25165824);
    unsigned short* x1  = (unsigned short*)((char*)d_ws + 26738688);
    unsigned short* w2b = (unsigned short*)((char*)d_ws + 28835840);

    prep_kernel<<<dim3(4896), dim3(256), 0, stream>>>(hs, spans, W1, W2, hp, w1b, w2b);
    // R6 measurement: gemm1 launched twice (idempotent). dur_us delta vs the
    // 145.3us single-launch baseline == t_gemm1.
    gemm1_gelu<<<dim3(512), dim3(256), 0, stream>>>(hp, w1b, b1, x1);
    gemm1_gelu<<<dim3(512), dim3(256), 0, stream>>>(hp, w1b, b1, x1);
    mlp2_head<<<dim3(128), dim3(256), 0, stream>>>(x1, w2b, b2, W3, b3, mask, out);
}

// Round 10
// 143.281 us; speedup vs baseline: 2.6195x; 1.1701x over previous
//
#include <hip/hip_runtime.h>
#include <hip/hip_bf16.h>
#include <math.h>

typedef __bf16 bf16x8 __attribute__((ext_vector_type(8)));
typedef float f32x4 __attribute__((ext_vector_type(4)));

__device__ __forceinline__ unsigned short f2bf(float x) {
    union { float f; unsigned int u; } v; v.f = x;
    unsigned int r = v.u + 0x7fffu + ((v.u >> 16) & 1u);  // round-to-nearest-even
    return (unsigned short)(r >> 16);
}
__device__ __forceinline__ float gelu_exact(float v) {
    return 0.5f * v * (1.0f + erff(v * 0.70710678118654752f));
}

// pool exactly N rows starting at s (N is a compile-time case; loads issued
// back-to-back, summed ascending -> identical fp order to the R2-verified path)
template<int N>
__device__ __forceinline__ void pool_sum(const float4* __restrict__ base, int s, int tid, float4& out) {
    float4 v[N];
#pragma unroll
    for (int t = 0; t < N; ++t) v[t] = base[(s + t) * 256 + tid];
    float x = 0.f, y = 0.f, z = 0.f, w = 0.f;
#pragma unroll
    for (int t = 0; t < N; ++t) { x += v[t].x; y += v[t].y; z += v[t].z; w += v[t].w; }
    const float inv = 1.0f / (float)N;
    out.x = x * inv; out.y = y * inv; out.z = z * inv; out.w = w * inv;
}

__device__ __forceinline__ void pool_dispatch(const float4* __restrict__ base, int s, int len, int tid, float4& out) {
    // len is wave-uniform (whole block shares one pair) -> uniform jump, no divergence
    switch (len) {
        case 1: pool_sum<1>(base, s, tid, out); break;
        case 2: pool_sum<2>(base, s, tid, out); break;
        case 3: pool_sum<3>(base, s, tid, out); break;
        case 4: pool_sum<4>(base, s, tid, out); break;
        case 5: pool_sum<5>(base, s, tid, out); break;
        case 6: pool_sum<6>(base, s, tid, out); break;
        case 7: pool_sum<7>(base, s, tid, out); break;
        default: pool_sum<8>(base, s, tid, out); break;
    }
}

// ---------------------------------------------------------------------------
// prep: blocks [0,4096)    -> span pooling into hp (4096 x 3072 bf16)
//       blocks [4096,4864) -> W1 fp32 -> bf16 (256x3072)
//       blocks [4864,4896) -> W2 fp32 -> bf16 (128x256)
// R10: batch->XCD clustering. The 256MB workspace re-poison fill evicts L3
// each iter, so hs reads are HBM-cold. Default dispatch round-robins the 128
// pairs of one batch across all 8 XCDs -> each XCD L2 fetches the same 2MB
// batch slice independently (~150MB HBM logical). Remap blk so batch b is
// handled entirely by XCD b%8 (4 batches/XCD, one hot slice at a time in its
// 4MB L2) -> HBM hs traffic ~58MB unique. [R4-verified pooling body]
// ---------------------------------------------------------------------------
__global__ __launch_bounds__(256) void prep_kernel(const float* __restrict__ hs,
                                                   const int* __restrict__ spans,
                                                   const float* __restrict__ W1,
                                                   const float* __restrict__ W2,
                                                   unsigned short* __restrict__ hp,
                                                   unsigned short* __restrict__ w1b,
                                                   unsigned short* __restrict__ w2b) {
    const int blk = blockIdx.x;
    const int tid = threadIdx.x;

    if (blk >= 4096) {
        if (blk < 4864) {                     // W1 convert: 196608 float4s
            const int i = (blk - 4096) * 256 + tid;
            float4 f = ((const float4*)W1)[i];
            ushort4 u;
            u.x = f2bf(f.x); u.y = f2bf(f.y); u.z = f2bf(f.z); u.w = f2bf(f.w);
            ((ushort4*)w1b)[i] = u;
        } else {                              // W2 convert: 8192 float4s
            const int i = (blk - 4864) * 256 + tid;
            float4 f = ((const float4*)W2)[i];
            ushort4 u;
            u.x = f2bf(f.x); u.y = f2bf(f.y); u.z = f2bf(f.z); u.w = f2bf(f.w);
            ((ushort4*)w2b)[i] = u;
        }
        return;
    }

    // batch->XCD clustering: blk = q*8 + x (x = XCD by round-robin dispatch).
    // XCD x handles batches {x, x+8, x+16, x+24}; q>>7 picks which, q&127 the pair.
    const int x = blk & 7;
    const int q = blk >> 3;                   // 0..511
    const int b = x + 8 * (q >> 7);           // batch 0..31
    const int pair = b * 128 + (q & 127);     // b*Q + q, Q=128

    // dtype probe: int64 spans -> word 1 is high half of asp_s[0] (== 0);
    // int32 spans -> it's asp_e[0] which is always >= 2.
    const bool is64 = (spans[1] == 0);
    int s_a, e_a, s_o, e_o;
    if (is64) {
        s_a = spans[(pair * 4 + 0) * 2]; e_a = spans[(pair * 4 + 1) * 2];
        s_o = spans[(pair * 4 + 2) * 2]; e_o = spans[(pair * 4 + 3) * 2];
    } else {
        s_a = spans[pair * 4 + 0]; e_a = spans[pair * 4 + 1];
        s_o = spans[pair * 4 + 2]; e_o = spans[pair * 4 + 3];
    }

    // invalid span -> pool over row 1 only (== sep token)
    if (!(s_a >= 2 && e_a >= s_a)) { s_a = 1; e_a = 1; }
    if (!(s_o >= 2 && e_o >= s_o)) { s_o = 1; e_o = 1; }
    const int lenA = e_a - s_a + 1;           // 1..8
    const int lenO = e_o - s_o + 1;           // 1..8

    const float4* base = (const float4*)hs + (size_t)b * 512 * 256;  // L=512, H/4=256

    float4 A, O;
    pool_dispatch(base, s_a, lenA, tid, A);
    pool_dispatch(base, s_o, lenO, tid, O);

    unsigned short* row = hp + (size_t)pair * 3072;
    const int d = tid * 4;
    ushort4 pa, po, pp;
    pa.x = f2bf(A.x); pa.y = f2bf(A.y); pa.z = f2bf(A.z); pa.w = f2bf(A.w);
    po.x = f2bf(O.x); po.y = f2bf(O.y); po.z = f2bf(O.z); po.w = f2bf(O.w);
    pp.x = f2bf(A.x * O.x); pp.y = f2bf(A.y * O.y);
    pp.z = f2bf(A.z * O.z); pp.w = f2bf(A.w * O.w);
    *(ushort4*)(row + d) = pa;
    *(ushort4*)(row + 1024 + d) = po;
    *(ushort4*)(row + 2048 + d) = pp;
}

// ---------------------------------------------------------------------------
// gemm1_gelu v4 (R4-verified): BM=32, BN=64, BK=192, grid 512 1-D, 2 blk/CU,
// XCD sibling co-location. Single launch (R6 double-launch probe reverted;
// measured t_gemm1 ~= 20-22us).
// ---------------------------------------------------------------------------
__global__ __launch_bounds__(256, 2) void gemm1_gelu(const unsigned short* __restrict__ A,
                                                     const unsigned short* __restrict__ Bw,
                                                     const float* __restrict__ b1,
                                                     unsigned short* __restrict__ x1) {
    __shared__ __align__(16) unsigned short As[2 * 32 * 192];   // 24 KB
    __shared__ __align__(16) unsigned short Bs[2 * 64 * 192];   // 48 KB

    const int tid = threadIdx.x;
    const int lane = tid & 63;
    const int wid = tid >> 6;
    const int quad = lane >> 4;
    const int l16 = lane & 15;

    // XCD co-location: id%8 = XCD; XCD k owns M-panels [k*16, k*16+16) x all 4 N
    const int id = blockIdx.x;                // 0..511
    const int xcd = id & 7;
    const int sub = id >> 3;                  // 0..63
    const int m0 = (xcd * 16 + (sub >> 2)) * 32;
    const int n0 = (sub & 3) * 64;

    // staging sources: slot s (16B) -> row = s/24, chunk c = s%24, XOR-swizzled
    const unsigned short* Aptr[3];
#pragma unroll
    for (int p = 0; p < 3; ++p) {
        const int s = p * 256 + tid;          // 0..767
        const int row = s / 24;
        const int c = s - row * 24;
        const int lch = (c & 24) | ((c & 7) ^ (row & 7));
        Aptr[p] = A + (size_t)(m0 + row) * 3072 + lch * 8;
    }
    const unsigned short* Bptr[6];
#pragma unroll
    for (int p = 0; p < 6; ++p) {
        const int s = p * 256 + tid;          // 0..1535
        const int row = s / 24;
        const int c = s - row * 24;
        const int lch = (c & 24) | ((c & 7) ^ (row & 7));
        Bptr[p] = Bw + (size_t)(n0 + row) * 3072 + lch * 8;
    }

    // fragment LDS offsets (halfwords): K-frag h (6 per iter), chunk c = h*4+quad
    int aoff[2][6], boff[6];
#pragma unroll
    for (int h = 0; h < 6; ++h) {
        const int c = h * 4 + quad;
#pragma unroll
        for (int mh = 0; mh < 2; ++mh) {
            const int row = mh * 16 + l16;
            const int pc = (c & 24) | ((c & 7) ^ (row & 7));
            aoff[mh][h] = row * 192 + pc * 8;
        }
        const int brow = wid * 16 + l16;
        const int pcb = (c & 24) | ((c & 7) ^ (brow & 7));
        boff[h] = brow * 192 + pcb * 8;
    }

    f32x4 acc[2] = {};

    // prologue: tile 0 -> buffer 0
#pragma unroll
    for (int p = 0; p < 3; ++p)
        __builtin_amdgcn_global_load_lds(
            (const __attribute__((address_space(1))) void*)Aptr[p],
            (__attribute__((address_space(3))) void*)(&As[(p * 256 + tid) * 8]), 16, 0, 0);
#pragma unroll
    for (int p = 0; p < 6; ++p)
        __builtin_amdgcn_global_load_lds(
            (const __attribute__((address_space(1))) void*)Bptr[p],
            (__attribute__((address_space(3))) void*)(&Bs[(p * 256 + tid) * 8]), 16, 0, 0);

    for (int it = 0; it < 16; ++it) {
        const int cur = it & 1;
        __syncthreads();                      // drains pending stage (vmcnt 0)
        if (it + 1 < 16) {
            const int nxt = cur ^ 1;
            const int kadv = (it + 1) * 192;  // halfwords along K
#pragma unroll
            for (int p = 0; p < 3; ++p)
                __builtin_amdgcn_global_load_lds(
                    (const __attribute__((address_space(1))) void*)(Aptr[p] + kadv),
                    (__attribute__((address_space(3))) void*)(&As[nxt * 6144 + (p * 256 + tid) * 8]), 16, 0, 0);
#pragma unroll
            for (int p = 0; p < 6; ++p)
                __builtin_amdgcn_global_load_lds(
                    (const __attribute__((address_space(1))) void*)(Bptr[p] + kadv),
                    (__attribute__((address_space(3))) void*)(&Bs[nxt * 12288 + (p * 256 + tid) * 8]), 16, 0, 0);
        }
#pragma unroll
        for (int h = 0; h < 6; ++h) {
            bf16x8 b = *(const bf16x8*)&Bs[cur * 12288 + boff[h]];
#pragma unroll
            for (int mh = 0; mh < 2; ++mh) {
                bf16x8 a = *(const bf16x8*)&As[cur * 6144 + aoff[mh][h]];
                acc[mh] = __builtin_amdgcn_mfma_f32_16x16x32_bf16(a, b, acc[mh], 0, 0, 0);
            }
        }
    }

    // epilogue: bias + gelu -> bf16; C/D map: col=l16, row=quad*4+reg
    const int n = n0 + wid * 16 + l16;
    const float bn = b1[n];
#pragma unroll
    for (int mh = 0; mh < 2; ++mh) {
#pragma unroll
        for (int rr = 0; rr < 4; ++rr) {
            const int m = m0 + mh * 16 + quad * 4 + rr;
            x1[(size_t)m * 256 + n] = f2bf(gelu_exact(acc[mh][rr] + bn));
        }
    }
}

// ---------------------------------------------------------------------------
// mlp2_head v2 (single-stage): 32 pairs/block, grid 128. (unchanged, verified)
// ---------------------------------------------------------------------------
__global__ __launch_bounds__(256) void mlp2_head(const unsigned short* __restrict__ x1,
                                                 const unsigned short* __restrict__ w2b,
                                                 const float* __restrict__ b2,
                                                 const float* __restrict__ W3,
                                                 const float* __restrict__ b3,
                                                 const float* __restrict__ mask,
                                                 float* __restrict__ out) {
    __shared__ __align__(16) unsigned char smem[98304];
    unsigned short* Xs = (unsigned short*)smem;            // 32 x 256 hw (swizzled)
    unsigned short* Ws = (unsigned short*)(smem + 16384);  // 128 x 256 hw (swizzled)
    float*          X2 = (float*)(smem + 81920);           // 32 x 128 fp32

    const int tid = threadIdx.x;
    const int lane = tid & 63;
    const int wid = tid >> 6;
    const int quad = lane >> 4;
    const int l16 = lane & 15;
    const int wM = (wid >> 1) * 16;   // waves 2x2: wave tile 16 pairs x 64 cols
    const int wN = (wid & 1) * 64;
    const int m0 = blockIdx.x * 32;

    // stage Xs: 1024 slots; slot s -> row=s>>5, c=s&31, swizzled source chunk
#pragma unroll
    for (int p = 0; p < 4; ++p) {
        const int s = p * 256 + tid;
        const int row = s >> 5;
        const int c = s & 31;
        const int lch = (c & 24) | ((c & 7) ^ (row & 7));
        __builtin_amdgcn_global_load_lds(
            (const __attribute__((address_space(1))) void*)(x1 + (size_t)(m0 + row) * 256 + lch * 8),
            (__attribute__((address_space(3))) void*)(&Xs[s * 8]), 16, 0, 0);
    }
    // stage Ws: 4096 slots
#pragma unroll
    for (int p = 0; p < 16; ++p) {
        const int s = p * 256 + tid;
        const int row = s >> 5;
        const int c = s & 31;
        const int lch = (c & 24) | ((c & 7) ^ (row & 7));
        __builtin_amdgcn_global_load_lds(
            (const __attribute__((address_space(1))) void*)(w2b + (size_t)row * 256 + lch * 8),
            (__attribute__((address_space(3))) void*)(&Ws[s * 8]), 16, 0, 0);
    }
    __syncthreads();

    // GEMM2: 8 K-frags, 4 MFMA each per wave
    f32x4 acc[4] = {};
#pragma unroll
    for (int h = 0; h < 8; ++h) {
        const int c = h * 4 + quad;
        const int rowa = wM + l16;
        const int pca = (c & 24) | ((c & 7) ^ (rowa & 7));
        bf16x8 a = *(const bf16x8*)&Xs[rowa * 256 + pca * 8];
#pragma unroll
        for (int ni = 0; ni < 4; ++ni) {
            const int rowb = wN + ni * 16 + l16;
            const int pcb = (c & 24) | ((c & 7) ^ (rowb & 7));
            bf16x8 b = *(const bf16x8*)&Ws[rowb * 256 + pcb * 8];
            acc[ni] = __builtin_amdgcn_mfma_f32_16x16x32_bf16(a, b, acc[ni], 0, 0, 0);
        }
    }

    // x2 = gelu(acc + b2) -> X2 (fp32 LDS)
#pragma unroll
    for (int ni = 0; ni < 4; ++ni) {
        const int n = wN + ni * 16 + l16;
        const float bn = b2[n];
#pragma unroll
        for (int rr = 0; rr < 4; ++rr) {
            const int m = wM + quad * 4 + rr;
            X2[m * 128 + n] = gelu_exact(acc[ni][rr] + bn);
        }
    }
    __syncthreads();

    // head: 8 threads per pair, 16 cols each
    const int p = tid >> 3;           // pair-in-block 0..31
    const int cc = (tid & 7) * 16;
    float a0 = 0.f, a1 = 0.f;
#pragma unroll
    for (int j = 0; j < 16; ++j) {
        const float xv = X2[p * 128 + cc + j];
        a0 += xv * W3[cc + j];
        a1 += xv * W3[128 + cc + j];
    }
    a0 += __shfl_xor(a0, 1); a0 += __shfl_xor(a0, 2); a0 += __shfl_xor(a0, 4);
    a1 += __shfl_xor(a1, 1); a1 += __shfl_xor(a1, 2); a1 += __shfl_xor(a1, 4);
    if ((tid & 7) == 0) {
        const int pair = m0 + p;
        const float mk = (mask[pair] >= 0.5f) ? 1.0f : 0.0f;
        out[pair * 2 + 0] = ((1.0f / (1.0f + expf(-(a0 + b3[0])))) * 8.0f + 1.0f) * mk;
        out[pair * 2 + 1] = ((1.0f / (1.0f + expf(-(a1 + b3[1])))) * 8.0f + 1.0f) * mk;
    }
}

// ---------------------------------------------------------------------------
extern "C" void kernel_launch(void* const* d_in, const int* in_sizes, int n_in,
                              void* d_out, int out_size, void* d_ws, size_t ws_size,
                              hipStream_t stream) {
    const float* hs   = (const float*)d_in[0];
    const int*   spans= (const int*)d_in[1];
    const float* mask = (const float*)d_in[2];
    const float* W1   = (const float*)d_in[3];
    const float* b1   = (const float*)d_in[4];
    const float* W2   = (const float*)d_in[5];
    const float* b2   = (const float*)d_in[6];
    const float* W3   = (const float*)d_in[7];
    const float* b3   = (const float*)d_in[8];
    float* out = (float*)d_out;

    // ws: hp bf16 4096x3072 [0, 25165824); w1b bf16 256x3072 [25165824, +1.5MB);
    // x1 bf16 4096x256 [26738688, +2MB); w2b bf16 128x256 [28835840, +64KB).
    unsigned short* hp  = (unsigned short*)d_ws;
    unsigned short* w1b = (unsigned short*)((char*)d_ws + 25165824);
    unsigned short* x1  = (unsigned short*)((char*)d_ws + 26738688);
    unsigned short* w2b = (unsigned short*)((char*)d_ws + 28835840);

    prep_kernel<<<dim3(4896), dim3(256), 0, stream>>>(hs, spans, W1, W2, hp, w1b, w2b);
    gemm1_gelu<<<dim3(512), dim3(256), 0, stream>>>(hp, w1b, b1, x1);
    mlp2_head<<<dim3(128), dim3(256), 0, stream>>>(x1, w2b, b2, W3, b3, mask, out);
}

// Round 11
// 143.045 us; speedup vs baseline: 2.6238x; 1.0017x over previous
//
#include <hip/hip_runtime.h>
#include <hip/hip_bf16.h>
#include <math.h>

typedef __bf16 bf16x8 __attribute__((ext_vector_type(8)));
typedef float f32x4 __attribute__((ext_vector_type(4)));

__device__ __forceinline__ unsigned short f2bf(float x) {
    union { float f; unsigned int u; } v; v.f = x;
    unsigned int r = v.u + 0x7fffu + ((v.u >> 16) & 1u);  // round-to-nearest-even
    return (unsigned short)(r >> 16);
}
__device__ __forceinline__ float gelu_exact(float v) {
    return 0.5f * v * (1.0f + erff(v * 0.70710678118654752f));
}

// pool exactly N rows starting at s (compile-time N; loads issued back-to-back,
// summed ascending -> identical fp order to the R2/R4-verified path)
template<int N>
__device__ __forceinline__ void pool_sum(const float4* __restrict__ base, int s, int t, float4& out) {
    float4 v[N];
#pragma unroll
    for (int k = 0; k < N; ++k) v[k] = base[(s + k) * 256 + t];
    float x = 0.f, y = 0.f, z = 0.f, w = 0.f;
#pragma unroll
    for (int k = 0; k < N; ++k) { x += v[k].x; y += v[k].y; z += v[k].z; w += v[k].w; }
    const float inv = 1.0f / (float)N;
    out.x = x * inv; out.y = y * inv; out.z = z * inv; out.w = w * inv;
}

__device__ __forceinline__ void pool_dispatch(const float4* __restrict__ base, int s, int len, int t, float4& out) {
    // len is uniform across the 256-thread half-block -> uniform jump, no divergence
    switch (len) {
        case 1: pool_sum<1>(base, s, t, out); break;
        case 2: pool_sum<2>(base, s, t, out); break;
        case 3: pool_sum<3>(base, s, t, out); break;
        case 4: pool_sum<4>(base, s, t, out); break;
        case 5: pool_sum<5>(base, s, t, out); break;
        case 6: pool_sum<6>(base, s, t, out); break;
        case 7: pool_sum<7>(base, s, t, out); break;
        default: pool_sum<8>(base, s, t, out); break;
    }
}

// ---------------------------------------------------------------------------
// prep R11: 512-thread blocks, 2 pairs/block (grid 2048 pool + 400 convert =
// 2448, was 4896 x 256). Mechanism: prep's measured 31us vs ~16us BW floor is
// attributed to block-granularity overhead (4896 blocks x ~0.4us lifetime:
// per-block drain + dispatch ramp + 800-trivial-block tail). Fatter blocks
// halve switch events; converts folded into 400 fat blocks kill the tail.
// Pair mapping: half-block (4 waves) per pair -> spans stay wave-uniform.
// Keeps R10 batch->XCD clustering + R4 exact-length dispatch (verified).
// ---------------------------------------------------------------------------
__global__ __launch_bounds__(512) void prep_kernel(const float* __restrict__ hs,
                                                   const int* __restrict__ spans,
                                                   const float* __restrict__ W1,
                                                   const float* __restrict__ W2,
                                                   unsigned short* __restrict__ hp,
                                                   unsigned short* __restrict__ w1b,
                                                   unsigned short* __restrict__ w2b) {
    const int blk = blockIdx.x;
    const int tid = threadIdx.x;              // 0..511

    if (blk >= 2048) {                        // converts: 400 blocks x 512 = 204800
        const int i = (blk - 2048) * 512 + tid;
        if (i < 196608) {                     // W1: 196608 float4s
            float4 f = ((const float4*)W1)[i];
            ushort4 u;
            u.x = f2bf(f.x); u.y = f2bf(f.y); u.z = f2bf(f.z); u.w = f2bf(f.w);
            ((ushort4*)w1b)[i] = u;
        } else {                              // W2: 8192 float4s
            const int j = i - 196608;
            float4 f = ((const float4*)W2)[j];
            ushort4 u;
            u.x = f2bf(f.x); u.y = f2bf(f.y); u.z = f2bf(f.z); u.w = f2bf(f.w);
            ((ushort4*)w2b)[j] = u;
        }
        return;
    }

    // batch->XCD clustering at 2-pair granularity: blk = q*8 + x; XCD x owns
    // batches {x, x+8, x+16, x+24}; q>>6 picks which, (q&63)*2+half the pair.
    const int x = blk & 7;
    const int q = blk >> 3;                   // 0..255
    const int b = x + 8 * (q >> 6);           // batch 0..31
    const int half = tid >> 8;                // 0 or 1 (4 waves each)
    const int pair = b * 128 + (q & 63) * 2 + half;
    const int t = tid & 255;                  // lane within the pair's 256 cols

    // dtype probe: int64 spans -> word 1 is high half of asp_s[0] (== 0);
    // int32 spans -> it's asp_e[0] which is always >= 2.
    const bool is64 = (spans[1] == 0);
    int s_a, e_a, s_o, e_o;
    if (is64) {
        s_a = spans[(pair * 4 + 0) * 2]; e_a = spans[(pair * 4 + 1) * 2];
        s_o = spans[(pair * 4 + 2) * 2]; e_o = spans[(pair * 4 + 3) * 2];
    } else {
        s_a = spans[pair * 4 + 0]; e_a = spans[pair * 4 + 1];
        s_o = spans[pair * 4 + 2]; e_o = spans[pair * 4 + 3];
    }

    // invalid span -> pool over row 1 only (== sep token)
    if (!(s_a >= 2 && e_a >= s_a)) { s_a = 1; e_a = 1; }
    if (!(s_o >= 2 && e_o >= s_o)) { s_o = 1; e_o = 1; }
    const int lenA = e_a - s_a + 1;           // 1..8
    const int lenO = e_o - s_o + 1;           // 1..8

    const float4* base = (const float4*)hs + (size_t)b * 512 * 256;  // L=512, H/4=256

    float4 A, O;
    pool_dispatch(base, s_a, lenA, t, A);
    pool_dispatch(base, s_o, lenO, t, O);

    unsigned short* row = hp + (size_t)pair * 3072;
    const int d = t * 4;
    ushort4 pa, po, pp;
    pa.x = f2bf(A.x); pa.y = f2bf(A.y); pa.z = f2bf(A.z); pa.w = f2bf(A.w);
    po.x = f2bf(O.x); po.y = f2bf(O.y); po.z = f2bf(O.z); po.w = f2bf(O.w);
    pp.x = f2bf(A.x * O.x); pp.y = f2bf(A.y * O.y);
    pp.z = f2bf(A.z * O.z); pp.w = f2bf(A.w * O.w);
    *(ushort4*)(row + d) = pa;
    *(ushort4*)(row + 1024 + d) = po;
    *(ushort4*)(row + 2048 + d) = pp;
}

// ---------------------------------------------------------------------------
// gemm1_gelu v4 (R4/R10-verified): BM=32, BN=64, BK=192, grid 512 1-D,
// 2 blk/CU, XCD sibling co-location. Staging-BW bound (~290MB logical L2/L3
// traffic in ~21us ~= 14 TB/s) -> near its structural floor; do not retune.
// ---------------------------------------------------------------------------
__global__ __launch_bounds__(256, 2) void gemm1_gelu(const unsigned short* __restrict__ A,
                                                     const unsigned short* __restrict__ Bw,
                                                     const float* __restrict__ b1,
                                                     unsigned short* __restrict__ x1) {
    __shared__ __align__(16) unsigned short As[2 * 32 * 192];   // 24 KB
    __shared__ __align__(16) unsigned short Bs[2 * 64 * 192];   // 48 KB

    const int tid = threadIdx.x;
    const int lane = tid & 63;
    const int wid = tid >> 6;
    const int quad = lane >> 4;
    const int l16 = lane & 15;

    // XCD co-location: id%8 = XCD; XCD k owns M-panels [k*16, k*16+16) x all 4 N
    const int id = blockIdx.x;                // 0..511
    const int xcd = id & 7;
    const int sub = id >> 3;                  // 0..63
    const int m0 = (xcd * 16 + (sub >> 2)) * 32;
    const int n0 = (sub & 3) * 64;

    // staging sources: slot s (16B) -> row = s/24, chunk c = s%24, XOR-swizzled
    const unsigned short* Aptr[3];
#pragma unroll
    for (int p = 0; p < 3; ++p) {
        const int s = p * 256 + tid;          // 0..767
        const int row = s / 24;
        const int c = s - row * 24;
        const int lch = (c & 24) | ((c & 7) ^ (row & 7));
        Aptr[p] = A + (size_t)(m0 + row) * 3072 + lch * 8;
    }
    const unsigned short* Bptr[6];
#pragma unroll
    for (int p = 0; p < 6; ++p) {
        const int s = p * 256 + tid;          // 0..1535
        const int row = s / 24;
        const int c = s - row * 24;
        const int lch = (c & 24) | ((c & 7) ^ (row & 7));
        Bptr[p] = Bw + (size_t)(n0 + row) * 3072 + lch * 8;
    }

    // fragment LDS offsets (halfwords): K-frag h (6 per iter), chunk c = h*4+quad
    int aoff[2][6], boff[6];
#pragma unroll
    for (int h = 0; h < 6; ++h) {
        const int c = h * 4 + quad;
#pragma unroll
        for (int mh = 0; mh < 2; ++mh) {
            const int row = mh * 16 + l16;
            const int pc = (c & 24) | ((c & 7) ^ (row & 7));
            aoff[mh][h] = row * 192 + pc * 8;
        }
        const int brow = wid * 16 + l16;
        const int pcb = (c & 24) | ((c & 7) ^ (brow & 7));
        boff[h] = brow * 192 + pcb * 8;
    }

    f32x4 acc[2] = {};

    // prologue: tile 0 -> buffer 0
#pragma unroll
    for (int p = 0; p < 3; ++p)
        __builtin_amdgcn_global_load_lds(
            (const __attribute__((address_space(1))) void*)Aptr[p],
            (__attribute__((address_space(3))) void*)(&As[(p * 256 + tid) * 8]), 16, 0, 0);
#pragma unroll
    for (int p = 0; p < 6; ++p)
        __builtin_amdgcn_global_load_lds(
            (const __attribute__((address_space(1))) void*)Bptr[p],
            (__attribute__((address_space(3))) void*)(&Bs[(p * 256 + tid) * 8]), 16, 0, 0);

    for (int it = 0; it < 16; ++it) {
        const int cur = it & 1;
        __syncthreads();                      // drains pending stage (vmcnt 0)
        if (it + 1 < 16) {
            const int nxt = cur ^ 1;
            const int kadv = (it + 1) * 192;  // halfwords along K
#pragma unroll
            for (int p = 0; p < 3; ++p)
                __builtin_amdgcn_global_load_lds(
                    (const __attribute__((address_space(1))) void*)(Aptr[p] + kadv),
                    (__attribute__((address_space(3))) void*)(&As[nxt * 6144 + (p * 256 + tid) * 8]), 16, 0, 0);
#pragma unroll
            for (int p = 0; p < 6; ++p)
                __builtin_amdgcn_global_load_lds(
                    (const __attribute__((address_space(1))) void*)(Bptr[p] + kadv),
                    (__attribute__((address_space(3))) void*)(&Bs[nxt * 12288 + (p * 256 + tid) * 8]), 16, 0, 0);
        }
#pragma unroll
        for (int h = 0; h < 6; ++h) {
            bf16x8 b = *(const bf16x8*)&Bs[cur * 12288 + boff[h]];
#pragma unroll
            for (int mh = 0; mh < 2; ++mh) {
                bf16x8 a = *(const bf16x8*)&As[cur * 6144 + aoff[mh][h]];
                acc[mh] = __builtin_amdgcn_mfma_f32_16x16x32_bf16(a, b, acc[mh], 0, 0, 0);
            }
        }
    }

    // epilogue: bias + gelu -> bf16; C/D map: col=l16, row=quad*4+reg
    const int n = n0 + wid * 16 + l16;
    const float bn = b1[n];
#pragma unroll
    for (int mh = 0; mh < 2; ++mh) {
#pragma unroll
        for (int rr = 0; rr < 4; ++rr) {
            const int m = m0 + mh * 16 + quad * 4 + rr;
            x1[(size_t)m * 256 + n] = f2bf(gelu_exact(acc[mh][rr] + bn));
        }
    }
}

// ---------------------------------------------------------------------------
// mlp2_head v2 (single-stage): 32 pairs/block, grid 128. (unchanged, verified)
// ---------------------------------------------------------------------------
__global__ __launch_bounds__(256) void mlp2_head(const unsigned short* __restrict__ x1,
                                                 const unsigned short* __restrict__ w2b,
                                                 const float* __restrict__ b2,
                                                 const float* __restrict__ W3,
                                                 const float* __restrict__ b3,
                                                 const float* __restrict__ mask,
                                                 float* __restrict__ out) {
    __shared__ __align__(16) unsigned char smem[98304];
    unsigned short* Xs = (unsigned short*)smem;            // 32 x 256 hw (swizzled)
    unsigned short* Ws = (unsigned short*)(smem + 16384);  // 128 x 256 hw (swizzled)
    float*          X2 = (float*)(smem + 81920);           // 32 x 128 fp32

    const int tid = threadIdx.x;
    const int lane = tid & 63;
    const int wid = tid >> 6;
    const int quad = lane >> 4;
    const int l16 = lane & 15;
    const int wM = (wid >> 1) * 16;   // waves 2x2: wave tile 16 pairs x 64 cols
    const int wN = (wid & 1) * 64;
    const int m0 = blockIdx.x * 32;

    // stage Xs: 1024 slots; slot s -> row=s>>5, c=s&31, swizzled source chunk
#pragma unroll
    for (int p = 0; p < 4; ++p) {
        const int s = p * 256 + tid;
        const int row = s >> 5;
        const int c = s & 31;
        const int lch = (c & 24) | ((c & 7) ^ (row & 7));
        __builtin_amdgcn_global_load_lds(
            (const __attribute__((address_space(1))) void*)(x1 + (size_t)(m0 + row) * 256 + lch * 8),
            (__attribute__((address_space(3))) void*)(&Xs[s * 8]), 16, 0, 0);
    }
    // stage Ws: 4096 slots
#pragma unroll
    for (int p = 0; p < 16; ++p) {
        const int s = p * 256 + tid;
        const int row = s >> 5;
        const int c = s & 31;
        const int lch = (c & 24) | ((c & 7) ^ (row & 7));
        __builtin_amdgcn_global_load_lds(
            (const __attribute__((address_space(1))) void*)(w2b + (size_t)row * 256 + lch * 8),
            (__attribute__((address_space(3))) void*)(&Ws[s * 8]), 16, 0, 0);
    }
    __syncthreads();

    // GEMM2: 8 K-frags, 4 MFMA each per wave
    f32x4 acc[4] = {};
#pragma unroll
    for (int h = 0; h < 8; ++h) {
        const int c = h * 4 + quad;
        const int rowa = wM + l16;
        const int pca = (c & 24) | ((c & 7) ^ (rowa & 7));
        bf16x8 a = *(const bf16x8*)&Xs[rowa * 256 + pca * 8];
#pragma unroll
        for (int ni = 0; ni < 4; ++ni) {
            const int rowb = wN + ni * 16 + l16;
            const int pcb = (c & 24) | ((c & 7) ^ (rowb & 7));
            bf16x8 b = *(const bf16x8*)&Ws[rowb * 256 + pcb * 8];
            acc[ni] = __builtin_amdgcn_mfma_f32_16x16x32_bf16(a, b, acc[ni], 0, 0, 0);
        }
    }

    // x2 = gelu(acc + b2) -> X2 (fp32 LDS)
#pragma unroll
    for (int ni = 0; ni < 4; ++ni) {
        const int n = wN + ni * 16 + l16;
        const float bn = b2[n];
#pragma unroll
        for (int rr = 0; rr < 4; ++rr) {
            const int m = wM + quad * 4 + rr;
            X2[m * 128 + n] = gelu_exact(acc[ni][rr] + bn);
        }
    }
    __syncthreads();

    // head: 8 threads per pair, 16 cols each
    const int p = tid >> 3;           // pair-in-block 0..31
    const int cc = (tid & 7) * 16;
    float a0 = 0.f, a1 = 0.f;
#pragma unroll
    for (int j = 0; j < 16; ++j) {
        const float xv = X2[p * 128 + cc + j];
        a0 += xv * W3[cc + j];
        a1 += xv * W3[128 + cc + j];
    }
    a0 += __shfl_xor(a0, 1); a0 += __shfl_xor(a0, 2); a0 += __shfl_xor(a0, 4);
    a1 += __shfl_xor(a1, 1); a1 += __shfl_xor(a1, 2); a1 += __shfl_xor(a1, 4);
    if ((tid & 7) == 0) {
        const int pair = m0 + p;
        const float mk = (mask[pair] >= 0.5f) ? 1.0f : 0.0f;
        out[pair * 2 + 0] = ((1.0f / (1.0f + expf(-(a0 + b3[0])))) * 8.0f + 1.0f) * mk;
        out[pair * 2 + 1] = ((1.0f / (1.0f + expf(-(a1 + b3[1])))) * 8.0f + 1.0f) * mk;
    }
}

// ---------------------------------------------------------------------------
extern "C" void kernel_launch(void* const* d_in, const int* in_sizes, int n_in,
                              void* d_out, int out_size, void* d_ws, size_t ws_size,
                              hipStream_t stream) {
    const float* hs   = (const float*)d_in[0];
    const int*   spans= (const int*)d_in[1];
    const float* mask = (const float*)d_in[2];
    const float* W1   = (const float*)d_in[3];
    const float* b1   = (const float*)d_in[4];
    const float* W2   = (const float*)d_in[5];
    const float* b2   = (const float*)d_in[6];
    const float* W3   = (const float*)d_in[7];
    const float* b3   = (const float*)d_in[8];
    float* out = (float*)d_out;

    // ws: hp bf16 4096x3072 [0, 25165824); w1b bf16 256x3072 [25165824, +1.5MB);
    // x1 bf16 4096x256 [26738688, +2MB); w2b bf16 128x256 [28835840, +64KB).
    unsigned short* hp  = (unsigned short*)d_ws;
    unsigned short* w1b = (unsigned short*)((char*)d_ws + 25165824);
    unsigned short* x1  = (unsigned short*)((char*)d_ws + 26738688);
    unsigned short* w2b = (unsigned short*)((char*)d_ws + 28835840);

    prep_kernel<<<dim3(2448), dim3(512), 0, stream>>>(hs, spans, W1, W2, hp, w1b, w2b);
    gemm1_gelu<<<dim3(512), dim3(256), 0, stream>>>(hp, w1b, b1, x1);
    mlp2_head<<<dim3(128), dim3(256), 0, stream>>>(x1, w2b, b2, W3, b3, mask, out);
}